// Round 1
// baseline (947.009 us; speedup 1.0000x reference)
//
#include <hip/hip_runtime.h>
#include <stdint.h>

#define N_   2048      // boxes per batch
#define NW   64        // u32 words per mask row (N_/32)
#define CLS  4
#define B_   4

// ---------------- Kernel A: pairwise IoU -> bitmask ----------------
// ov[b][i][w] bit k set iff IoU(box i, box w*32+k) > thr  (within batch b)
__global__ __launch_bounds__(256) void build_mask(
    const float4* __restrict__ boxes, const float* __restrict__ thr_p,
    uint32_t* __restrict__ ov)
{
  __shared__ float4 sb[N_];                 // 32 KiB: all boxes of this batch
  const int b    = blockIdx.x >> 5;         // 32 row-tiles per batch
  const int tile = blockIdx.x & 31;
  const float thr = thr_p[0];
  for (int i = threadIdx.x; i < N_; i += 256) sb[i] = boxes[b * N_ + i];
  __syncthreads();
  // 64 rows x 64 words = 4096 tasks, 16 per thread
  for (int t = threadIdx.x; t < 64 * NW; t += 256) {
    const int r = tile * 64 + (t >> 6);
    const int w = t & (NW - 1);
    const float4 bi = sb[r];
    const float areai = (bi.z - bi.x) * (bi.w - bi.y);
    uint32_t bits = 0u;
    #pragma unroll 8
    for (int k = 0; k < 32; ++k) {
      const float4 bj = sb[w * 32 + k];
      const float xx1 = fmaxf(bi.x, bj.x);
      const float yy1 = fmaxf(bi.y, bj.y);
      const float xx2 = fminf(bi.z, bj.z);
      const float yy2 = fminf(bi.w, bj.w);
      const float iw = fmaxf(xx2 - xx1, 0.0f);
      const float ih = fmaxf(yy2 - yy1, 0.0f);
      const float inter = iw * ih;
      const float areaj = (bj.z - bj.x) * (bj.w - bj.y);
      const float uni = fmaxf(areai + areaj - inter, 1e-6f);
      if (inter / uni > thr) bits |= (1u << k);   // same op order as reference
    }
    ov[((size_t)(b * N_ + r)) * NW + w] = bits;
  }
}

// ---------------- Kernel B: per-(b,c) bitonic argsort (desc) + match init ----
__global__ __launch_bounds__(256) void argsort_init(
    const float* __restrict__ scores, int* __restrict__ order,
    int* __restrict__ match)
{
  __shared__ float sk[N_];
  __shared__ int   sv[N_];
  const int bc = blockIdx.x;                // b*CLS + c
  const float* s = scores + (size_t)bc * N_;
  for (int i = threadIdx.x; i < N_; i += 256) {
    sk[i] = s[i];
    sv[i] = i;
    match[(size_t)bc * N_ + i] = -1;        // default: unmatched
  }
  for (int size = 2; size <= N_; size <<= 1) {
    for (int stride = size >> 1; stride > 0; stride >>= 1) {
      __syncthreads();
      for (int t = threadIdx.x; t < N_ / 2; t += 256) {
        const int pos = 2 * t - (t & (stride - 1));
        const bool desc = ((t & (size >> 1)) == 0);
        const float ka = sk[pos], kb = sk[pos + stride];
        const int   va = sv[pos], vb = sv[pos + stride];
        // descending by score, ties -> smaller original index first (stable)
        const bool aBeforeB = (ka > kb) || (ka == kb && va < vb);
        if (desc != aBeforeB) {
          sk[pos] = kb; sk[pos + stride] = ka;
          sv[pos] = vb; sv[pos + stride] = va;
        }
      }
    }
  }
  __syncthreads();
  for (int i = threadIdx.x; i < N_; i += 256)
    order[(size_t)bc * N_ + i] = sv[i];
}

// ---------------- Kernel C: greedy scan, one wave per (b,c) -----------------
// Lane l owns suppression word l (boxes l*32 .. l*32+31) in a register.
// Mask rows for upcoming candidates are prefetched P iterations ahead so the
// per-iteration critical path is ballot + and/or, not the L3 row load.
__global__ __launch_bounds__(64) void nms_scan(
    const float* __restrict__ scores, const float* __restrict__ sthr_p,
    const int* __restrict__ order, const uint32_t* __restrict__ ov,
    int* __restrict__ match)
{
  const int bc = blockIdx.x;                // b*CLS + c
  const int b  = bc / CLS;
  const int l  = threadIdx.x;               // word index 0..63
  const float sthr = sthr_p[0];
  const float* s  = scores + (size_t)bc * N_;
  int* mt         = match  + (size_t)bc * N_;
  const int* ord  = order  + (size_t)bc * N_;
  const uint32_t* rowb = ov + (size_t)b * N_ * NW;

  // suppressed0: score <= sthr  (those boxes never match, never lead)
  uint32_t sup = 0u;
  #pragma unroll
  for (int k = 0; k < 32; ++k)
    if (!(s[l * 32 + k] > sthr)) sup |= (1u << k);

  constexpr int P = 16;                     // prefetch depth
  int      candbuf[P];
  uint32_t rowbuf[P];
  #pragma unroll
  for (int p = 0; p < P; ++p) {
    const int c = ord[p];
    candbuf[p] = c;
    rowbuf[p]  = rowb[(size_t)c * NW + l];
  }

  for (int it = 0; it < N_; it += P) {
    #pragma unroll
    for (int p = 0; p < P; ++p) {
      const int i = it + p;
      const int cand     = candbuf[p];
      const uint32_t row = rowbuf[p];
      if (i + P < N_) {                     // uniform branch
        const int cn = ord[i + P];
        candbuf[p] = cn;
        rowbuf[p]  = rowb[(size_t)cn * NW + l];
      }
      // is cand already suppressed?  (owner lane checks its bit; ballot broadcasts)
      const bool mine = (l == (cand >> 5)) && ((sup >> (cand & 31)) & 1u);
      if (!__any(mine)) {
        // cand is a leader: claim all unsuppressed overlapping boxes
        const uint32_t newm = row & ~sup;
        sup |= newm;
        uint32_t bits = newm;
        while (bits) {                      // typically 0-2 bits per lane
          const int k = __ffs(bits) - 1;
          bits &= bits - 1;
          mt[l * 32 + k] = cand;
        }
      }
    }
  }
}

extern "C" void kernel_launch(void* const* d_in, const int* in_sizes, int n_in,
                              void* d_out, int out_size, void* d_ws, size_t ws_size,
                              hipStream_t stream)
{
  const float4* boxes  = (const float4*)d_in[0];   // [B,N,4] f32
  const float*  scores = (const float*)d_in[1];    // [B,C,N] f32
  const float*  iouthr = (const float*)d_in[2];    // [1]
  const float*  scthr  = (const float*)d_in[3];    // [1]
  int* match = (int*)d_out;                        // [B,C,N] int32

  uint32_t* ov    = (uint32_t*)d_ws;                                   // 2 MiB
  int*      order = (int*)((char*)d_ws + (size_t)B_ * N_ * NW * sizeof(uint32_t));

  build_mask  <<<dim3(B_ * (N_ / 64)), dim3(256), 0, stream>>>(boxes, iouthr, ov);
  argsort_init<<<dim3(B_ * CLS),       dim3(256), 0, stream>>>(scores, order, match);
  nms_scan    <<<dim3(B_ * CLS),       dim3(64),  0, stream>>>(scores, scthr, order, ov, match);
}

// Round 2
// 386.175 us; speedup vs baseline: 2.4523x; 2.4523x over previous
//
#include <hip/hip_runtime.h>
#include <stdint.h>

#define N_   2048      // boxes per batch
#define NW   64        // u32 words per mask row (N_/32)
#define CLS  4
#define B_   4

// ---------------- Kernel A: pairwise IoU -> bitmask ----------------
// ov[b][i][w] bit k set iff IoU(box i, box w*32+k) > thr  (within batch b)
__global__ __launch_bounds__(256) void build_mask(
    const float4* __restrict__ boxes, const float* __restrict__ thr_p,
    uint32_t* __restrict__ ov)
{
  __shared__ float4 sb[N_];                 // 32 KiB: all boxes of this batch
  const int b    = blockIdx.x >> 5;         // 32 row-tiles per batch
  const int tile = blockIdx.x & 31;
  const float thr = thr_p[0];
  for (int i = threadIdx.x; i < N_; i += 256) sb[i] = boxes[b * N_ + i];
  __syncthreads();
  // 64 rows x 64 words = 4096 tasks, 16 per thread
  for (int t = threadIdx.x; t < 64 * NW; t += 256) {
    const int r = tile * 64 + (t >> 6);
    const int w = t & (NW - 1);
    const float4 bi = sb[r];
    const float areai = (bi.z - bi.x) * (bi.w - bi.y);
    uint32_t bits = 0u;
    #pragma unroll 8
    for (int k = 0; k < 32; ++k) {
      const float4 bj = sb[w * 32 + k];
      const float xx1 = fmaxf(bi.x, bj.x);
      const float yy1 = fmaxf(bi.y, bj.y);
      const float xx2 = fminf(bi.z, bj.z);
      const float yy2 = fminf(bi.w, bj.w);
      const float iw = fmaxf(xx2 - xx1, 0.0f);
      const float ih = fmaxf(yy2 - yy1, 0.0f);
      const float inter = iw * ih;
      const float areaj = (bj.z - bj.x) * (bj.w - bj.y);
      const float uni = fmaxf(areai + areaj - inter, 1e-6f);
      if (inter / uni > thr) bits |= (1u << k);   // same op order as reference
    }
    ov[((size_t)(b * N_ + r)) * NW + w] = bits;
  }
}

// ---------------- Kernel B: per-(b,c) bitonic argsort (desc) + match init ----
__global__ __launch_bounds__(256) void argsort_init(
    const float* __restrict__ scores, int* __restrict__ order,
    int* __restrict__ match)
{
  __shared__ float sk[N_];
  __shared__ int   sv[N_];
  const int bc = blockIdx.x;                // b*CLS + c
  const float* s = scores + (size_t)bc * N_;
  for (int i = threadIdx.x; i < N_; i += 256) {
    sk[i] = s[i];
    sv[i] = i;
    match[(size_t)bc * N_ + i] = -1;        // default: unmatched
  }
  for (int size = 2; size <= N_; size <<= 1) {
    for (int stride = size >> 1; stride > 0; stride >>= 1) {
      __syncthreads();
      for (int t = threadIdx.x; t < N_ / 2; t += 256) {
        const int pos = 2 * t - (t & (stride - 1));
        const bool desc = ((t & (size >> 1)) == 0);
        const float ka = sk[pos], kb = sk[pos + stride];
        const int   va = sv[pos], vb = sv[pos + stride];
        // descending by score, ties -> smaller original index first (stable)
        const bool aBeforeB = (ka > kb) || (ka == kb && va < vb);
        if (desc != aBeforeB) {
          sk[pos] = kb; sk[pos + stride] = ka;
          sv[pos] = vb; sv[pos + stride] = va;
        }
      }
    }
  }
  __syncthreads();
  for (int i = threadIdx.x; i < N_; i += 256)
    order[(size_t)bc * N_ + i] = sv[i];
}

// ---------------- Kernel C: greedy scan, one wave per (b,c) -----------------
// Lane l owns suppression word l (boxes l*32 .. l*32+31) in a register.
// Three-stage pipeline over blocks of P candidates:
//   - ord values for block t+2 fetched during block t  (so row addresses are
//     register-resident one full block before the row loads are issued)
//   - mask rows for block t+1 issued at start of block t
//   - block t processed with rows that have had a full block (~P*40cy) to land
// Per-iteration critical path: sup-update + ballot only.
__global__ __launch_bounds__(64) void nms_scan(
    const float* __restrict__ scores, const float* __restrict__ sthr_p,
    const int* __restrict__ order, const uint32_t* __restrict__ ov,
    int* __restrict__ match)
{
  const int bc = blockIdx.x;                // b*CLS + c
  const int b  = bc / CLS;
  const int l  = threadIdx.x;               // word index 0..63
  const float sthr = sthr_p[0];
  const float* s  = scores + (size_t)bc * N_;
  int* mt         = match  + (size_t)bc * N_;
  const int* ord  = order  + (size_t)bc * N_;
  const uint32_t* rowb = ov + (size_t)b * N_ * NW;

  // suppressed0: score <= sthr  (those boxes never match, never lead)
  uint32_t sup = 0u;
  const float4* s4 = (const float4*)(s + l * 32);
  #pragma unroll
  for (int q = 0; q < 8; ++q) {
    const float4 v = s4[q];
    if (!(v.x > sthr)) sup |= (1u << (4 * q + 0));
    if (!(v.y > sthr)) sup |= (1u << (4 * q + 1));
    if (!(v.z > sthr)) sup |= (1u << (4 * q + 2));
    if (!(v.w > sthr)) sup |= (1u << (4 * q + 3));
  }

  constexpr int P = 16;                     // pipeline block size
  int      cand_cur[P], cand_nxt[P], cand_n2[P];
  uint32_t row_cur[P], row_nxt[P];

  #pragma unroll
  for (int p = 0; p < P; ++p) cand_cur[p] = ord[p];
  #pragma unroll
  for (int p = 0; p < P; ++p) cand_nxt[p] = ord[P + p];
  #pragma unroll
  for (int p = 0; p < P; ++p) row_cur[p] = rowb[(size_t)cand_cur[p] * NW + l];

  for (int base = 0; base < N_; base += P) {
    // stage 1: issue rows for block t+1 (addresses already in registers)
    if (base + 2 * P <= N_) {
      #pragma unroll
      for (int p = 0; p < P; ++p)
        row_nxt[p] = rowb[(size_t)cand_nxt[p] * NW + l];
    } else {
      #pragma unroll
      for (int p = 0; p < P; ++p) row_nxt[p] = 0u;
    }
    // stage 0: fetch ord values for block t+2
    if (base + 3 * P <= N_) {
      #pragma unroll
      for (int p = 0; p < P; ++p) cand_n2[p] = ord[base + 2 * P + p];
    } else {
      #pragma unroll
      for (int p = 0; p < P; ++p) cand_n2[p] = 0;
    }
    // stage 2: process block t
    #pragma unroll
    for (int p = 0; p < P; ++p) {
      const int cand     = cand_cur[p];
      const uint32_t row = row_cur[p];
      // is cand already suppressed? (owner lane checks its bit; ballot broadcasts)
      const bool mine = (l == (cand >> 5)) && ((sup >> (cand & 31)) & 1u);
      if (!__any(mine)) {
        // cand is a leader: claim all unsuppressed overlapping boxes
        const uint32_t newm = row & ~sup;
        sup |= newm;
        uint32_t bits = newm;
        while (bits) {                      // typically 0-2 bits per lane
          const int k = __ffs(bits) - 1;
          bits &= bits - 1;
          mt[(l << 5) + k] = cand;
        }
      }
    }
    // rotate pipeline registers
    #pragma unroll
    for (int p = 0; p < P; ++p) {
      cand_cur[p] = cand_nxt[p];
      cand_nxt[p] = cand_n2[p];
      row_cur[p]  = row_nxt[p];
    }
  }
}

extern "C" void kernel_launch(void* const* d_in, const int* in_sizes, int n_in,
                              void* d_out, int out_size, void* d_ws, size_t ws_size,
                              hipStream_t stream)
{
  const float4* boxes  = (const float4*)d_in[0];   // [B,N,4] f32
  const float*  scores = (const float*)d_in[1];    // [B,C,N] f32
  const float*  iouthr = (const float*)d_in[2];    // [1]
  const float*  scthr  = (const float*)d_in[3];    // [1]
  int* match = (int*)d_out;                        // [B,C,N] int32

  uint32_t* ov    = (uint32_t*)d_ws;                                   // 2 MiB
  int*      order = (int*)((char*)d_ws + (size_t)B_ * N_ * NW * sizeof(uint32_t));

  build_mask  <<<dim3(B_ * (N_ / 64)), dim3(256), 0, stream>>>(boxes, iouthr, ov);
  argsort_init<<<dim3(B_ * CLS),       dim3(256), 0, stream>>>(scores, order, match);
  nms_scan    <<<dim3(B_ * CLS),       dim3(64),  0, stream>>>(scores, scthr, order, ov, match);
}

// Round 3
// 330.277 us; speedup vs baseline: 2.8673x; 1.1692x over previous
//
#include <hip/hip_runtime.h>
#include <stdint.h>

#define N_   2048      // boxes per batch
#define NW   64        // u32 words per mask row (N_/32)
#define CLS  4
#define B_   4

typedef uint32_t u32x32 __attribute__((ext_vector_type(32)));
typedef int      i32x32 __attribute__((ext_vector_type(32)));

// ---------------- Kernel A: pairwise IoU -> bitmask ----------------
// ov[b][i][w] bit k set iff IoU(box i, box w*32+k) > thr  (within batch b)
__global__ __launch_bounds__(256) void build_mask(
    const float4* __restrict__ boxes, const float* __restrict__ thr_p,
    uint32_t* __restrict__ ov)
{
  __shared__ float4 sb[N_];                 // 32 KiB: all boxes of this batch
  const int b    = blockIdx.x >> 5;         // 32 row-tiles per batch
  const int tile = blockIdx.x & 31;
  const float thr = thr_p[0];
  for (int i = threadIdx.x; i < N_; i += 256) sb[i] = boxes[b * N_ + i];
  __syncthreads();
  for (int t = threadIdx.x; t < 64 * NW; t += 256) {
    const int r = tile * 64 + (t >> 6);
    const int w = t & (NW - 1);
    const float4 bi = sb[r];
    const float areai = (bi.z - bi.x) * (bi.w - bi.y);
    uint32_t bits = 0u;
    #pragma unroll 8
    for (int k = 0; k < 32; ++k) {
      const float4 bj = sb[w * 32 + k];
      const float xx1 = fmaxf(bi.x, bj.x);
      const float yy1 = fmaxf(bi.y, bj.y);
      const float xx2 = fminf(bi.z, bj.z);
      const float yy2 = fminf(bi.w, bj.w);
      const float iw = fmaxf(xx2 - xx1, 0.0f);
      const float ih = fmaxf(yy2 - yy1, 0.0f);
      const float inter = iw * ih;
      const float areaj = (bj.z - bj.x) * (bj.w - bj.y);
      const float uni = fmaxf(areai + areaj - inter, 1e-6f);
      if (inter / uni > thr) bits |= (1u << k);   // same op order as reference
    }
    ov[((size_t)(b * N_ + r)) * NW + w] = bits;
  }
}

// ---------------- Kernel B: fused per-(b,c) argsort + greedy scan -----------
// Phase 1 (256 thr): load scores->LDS, build suppressed0 bits via ballot,
//                    bitonic argsort (desc, stable) in LDS, match_s = -1.
// Phase 2 (wave 0) : greedy scan. Lane l owns suppression word l in a reg.
//   Double-buffered row pipeline with 2-block lookahead:
//     end of block t issues rows for block t+2 (vmcnt wait = 63-p, encodable);
//     candidates re-read from LDS each block (cheap, no carried cand regs).
//   Match claims go to LDS (ds_write) so vmcnt stream = row loads ONLY.
// Phase 3 (256 thr): match_s -> global, coalesced int4.

// read 32 sorted candidate indices of block `blk` into an i32x32
#define LOADC(dst, blk) do {                                                  \
  _Pragma("unroll")                                                           \
  for (int j_ = 0; j_ < 8; ++j_) {                                            \
    const int4 v_ = ordv[(blk) * 8 + j_];                                     \
    dst[4*j_+0] = v_.x; dst[4*j_+1] = v_.y;                                   \
    dst[4*j_+2] = v_.z; dst[4*j_+3] = v_.w;                                   \
  }                                                                           \
} while (0)

// issue the 32 row loads for candidate vector cvec into row vector dst
#define ISSUE(dst, cvec) do {                                                 \
  _Pragma("unroll")                                                           \
  for (int p_ = 0; p_ < 32; ++p_)                                             \
    dst[p_] = rowb[(((size_t)(uint32_t)cvec[p_]) << 6) | (uint32_t)l];        \
  __builtin_amdgcn_sched_barrier(0);                                          \
} while (0)

// greedy-process one block of 32 candidates (branchless sup update)
#define PROCESS(cvec, rvec) do {                                              \
  _Pragma("unroll")                                                           \
  for (int p_ = 0; p_ < 32; ++p_) {                                           \
    const int      cand_ = cvec[p_];                                          \
    const uint32_t row_  = rvec[p_];                                          \
    const unsigned long long bal_ =                                           \
        __ballot(((sup >> (cand_ & 31)) & 1u) != 0u);                         \
    const uint32_t keep_ =                                                    \
        (((bal_ >> (cand_ >> 5)) & 1ull) == 0ull) ? 0xFFFFFFFFu : 0u;         \
    const uint32_t newm_ = row_ & ~sup & keep_;                               \
    sup |= newm_;                                                             \
    uint32_t bits_ = newm_;                                                   \
    while (bits_) {                                                           \
      const int k_ = __ffs(bits_) - 1;                                        \
      bits_ &= bits_ - 1;                                                     \
      match_s[(l << 5) + k_] = cand_;                                         \
    }                                                                         \
  }                                                                           \
} while (0)

__global__ __launch_bounds__(256, 1) void sort_scan(
    const float* __restrict__ scores, const float* __restrict__ sthr_p,
    const uint32_t* __restrict__ ov, int* __restrict__ match)
{
  __shared__ float sk[N_];
  __shared__ __align__(16) int sv[N_];
  __shared__ __align__(16) int match_s[N_];
  __shared__ uint32_t sup0[NW];

  const int bc = blockIdx.x;                // b*CLS + c
  const int b  = bc / CLS;
  const float sthr = sthr_p[0];
  const float* s = scores + (size_t)bc * N_;

  // ---- phase 1: load + suppressed0 ballot + init ----
  for (int i = threadIdx.x; i < N_; i += 256) {
    const float v = s[i];
    sk[i] = v;
    sv[i] = i;
    match_s[i] = -1;
    const unsigned long long bal = __ballot(v <= sthr);
    if ((threadIdx.x & 63) == 0) {          // i here is a multiple of 64
      sup0[(i >> 5)]     = (uint32_t)bal;
      sup0[(i >> 5) + 1] = (uint32_t)(bal >> 32);
    }
  }
  // bitonic sort: descending by score, ties -> smaller index first (stable)
  for (int size = 2; size <= N_; size <<= 1) {
    for (int stride = size >> 1; stride > 0; stride >>= 1) {
      __syncthreads();
      for (int t = threadIdx.x; t < N_ / 2; t += 256) {
        const int pos = 2 * t - (t & (stride - 1));
        const bool desc = ((t & (size >> 1)) == 0);
        const float ka = sk[pos], kb = sk[pos + stride];
        const int   va = sv[pos], vb = sv[pos + stride];
        const bool aBeforeB = (ka > kb) || (ka == kb && va < vb);
        if (desc != aBeforeB) {
          sk[pos] = kb; sk[pos + stride] = ka;
          sv[pos] = vb; sv[pos + stride] = va;
        }
      }
    }
  }
  __syncthreads();

  // ---- phase 2: greedy scan on wave 0 ----
  if (threadIdx.x < 64) {
    const int l = threadIdx.x;              // word index 0..63
    const uint32_t* rowb = ov + (size_t)b * N_ * NW;
    const int4* ordv = (const int4*)sv;
    uint32_t sup = sup0[l];

    u32x32 rE, rO;
    {   // prologue: issue rows for blocks 0 and 1
      i32x32 c0, c1;
      LOADC(c0, 0);
      LOADC(c1, 1);
      ISSUE(rE, c0);
      ISSUE(rO, c1);
    }
    for (int t = 0; t < 62; t += 2) {
      {   // even block t: consume rE, refill with rows of block t+2
        i32x32 cp, cn;
        LOADC(cp, t);
        LOADC(cn, t + 2);
        PROCESS(cp, rE);
        ISSUE(rE, cn);
      }
      {   // odd block t+1: consume rO, refill with rows of block t+3
        i32x32 cp, cn;
        LOADC(cp, t + 1);
        LOADC(cn, t + 3);
        PROCESS(cp, rO);
        ISSUE(rO, cn);
      }
    }
    {   // epilogue: blocks 62 (rE) and 63 (rO), no more issues
      i32x32 cp;
      LOADC(cp, 62);
      PROCESS(cp, rE);
      LOADC(cp, 63);
      PROCESS(cp, rO);
    }
  }
  __syncthreads();

  // ---- phase 3: coalesced writeout ----
  int4* mg = (int4*)(match + (size_t)bc * N_);
  const int4* ms = (const int4*)match_s;
  for (int i = threadIdx.x; i < N_ / 4; i += 256) mg[i] = ms[i];
}

extern "C" void kernel_launch(void* const* d_in, const int* in_sizes, int n_in,
                              void* d_out, int out_size, void* d_ws, size_t ws_size,
                              hipStream_t stream)
{
  const float4* boxes  = (const float4*)d_in[0];   // [B,N,4] f32
  const float*  scores = (const float*)d_in[1];    // [B,C,N] f32
  const float*  iouthr = (const float*)d_in[2];    // [1]
  const float*  scthr  = (const float*)d_in[3];    // [1]
  int* match = (int*)d_out;                        // [B,C,N] int32

  uint32_t* ov = (uint32_t*)d_ws;                  // 2 MiB mask

  build_mask<<<dim3(B_ * (N_ / 64)), dim3(256), 0, stream>>>(boxes, iouthr, ov);
  sort_scan <<<dim3(B_ * CLS),       dim3(256), 0, stream>>>(scores, scthr, ov, match);
}

// Round 4
// 316.611 us; speedup vs baseline: 2.9911x; 1.0432x over previous
//
#include <hip/hip_runtime.h>
#include <stdint.h>

#define N_   2048      // boxes per batch
#define NW   64        // u32 words per mask row (N_/32)
#define CLS  4
#define B_   4

// ---------------- Kernel A: pairwise IoU -> bitmask ----------------
// ov[b][i][w] bit k set iff IoU(box i, box w*32+k) > thr  (within batch b)
// 256 blocks (32 rows each) so all 256 CUs are busy.
__global__ __launch_bounds__(256) void build_mask(
    const float4* __restrict__ boxes, const float* __restrict__ thr_p,
    uint32_t* __restrict__ ov)
{
  __shared__ float4 sb[N_];                 // 32 KiB: all boxes of this batch
  const int b    = blockIdx.x >> 6;         // 64 row-tiles per batch
  const int tile = blockIdx.x & 63;         // 32 rows per tile
  const float thr = thr_p[0];
  for (int i = threadIdx.x; i < N_; i += 256) sb[i] = boxes[b * N_ + i];
  __syncthreads();
  // 32 rows x 64 words = 2048 tasks, 8 per thread
  for (int t = threadIdx.x; t < 32 * NW; t += 256) {
    const int r = tile * 32 + (t >> 6);
    const int w = t & (NW - 1);
    const float4 bi = sb[r];
    const float areai = (bi.z - bi.x) * (bi.w - bi.y);
    uint32_t bits = 0u;
    #pragma unroll 8
    for (int k = 0; k < 32; ++k) {
      const float4 bj = sb[w * 32 + k];
      const float xx1 = fmaxf(bi.x, bj.x);
      const float yy1 = fmaxf(bi.y, bj.y);
      const float xx2 = fminf(bi.z, bj.z);
      const float yy2 = fminf(bi.w, bj.w);
      const float iw = fmaxf(xx2 - xx1, 0.0f);
      const float ih = fmaxf(yy2 - yy1, 0.0f);
      const float inter = iw * ih;
      const float areaj = (bj.z - bj.x) * (bj.w - bj.y);
      const float uni = fmaxf(areai + areaj - inter, 1e-6f);
      if (inter / uni > thr) bits |= (1u << k);   // same op order as reference
    }
    ov[((size_t)(b * N_ + r)) * NW + w] = bits;
  }
}

// ---------------- Kernel B: fused per-(b,c) argsort + greedy scan -----------
// Phase 2 scan: lane l owns suppression word l in a register. Row loads are
// inline-asm global_load_dword (SGPR base + 32-bit voffset) so the compiler
// CANNOT sink/remat them; completion enforced by hand-counted vmcnt waits
// (loads retire in order -> vmcnt(32) proves the oldest 16 landed).
// Depth-3 pipeline, P=16: issue block t+3 after processing t; <=48 in flight.
// Match claims go to LDS so the vmcnt stream contains ONLY the row loads.

#define WAITV(n_) do {                                                        \
  asm volatile("s_waitcnt vmcnt(" #n_ ")" ::: "memory");                      \
  __builtin_amdgcn_sched_barrier(0);                                          \
} while (0)

// issue the 16 row loads of candidate block `blk` into buf[0..15]
#define ISSUE16(buf, blk) do {                                                \
  _Pragma("unroll")                                                           \
  for (int j_ = 0; j_ < 4; ++j_) {                                            \
    const int4 c4_ = ordv[(blk) * 4 + j_];                                    \
    asm volatile("global_load_dword %0, %1, %2"                               \
      : "=v"(buf[4*j_+0]) : "v"((c4_.x << 8) + l4), "s"(basep));              \
    asm volatile("global_load_dword %0, %1, %2"                               \
      : "=v"(buf[4*j_+1]) : "v"((c4_.y << 8) + l4), "s"(basep));              \
    asm volatile("global_load_dword %0, %1, %2"                               \
      : "=v"(buf[4*j_+2]) : "v"((c4_.z << 8) + l4), "s"(basep));              \
    asm volatile("global_load_dword %0, %1, %2"                               \
      : "=v"(buf[4*j_+3]) : "v"((c4_.w << 8) + l4), "s"(basep));              \
  }                                                                           \
} while (0)

// greedy step for one candidate (branchless sup update; validated round 2/3)
#define STEP(cand_, row_) do {                                                \
  const unsigned long long bal_ =                                             \
      __ballot(((sup >> ((cand_) & 31)) & 1u) != 0u);                         \
  const uint32_t keep_ =                                                      \
      (((bal_ >> ((cand_) >> 5)) & 1ull) == 0ull) ? 0xFFFFFFFFu : 0u;         \
  const uint32_t newm_ = (row_) & ~sup & keep_;                               \
  sup |= newm_;                                                               \
  uint32_t bits_ = newm_;                                                     \
  while (bits_) {                                                             \
    const int k_ = __ffs(bits_) - 1;                                          \
    bits_ &= bits_ - 1;                                                       \
    match_s[(l << 5) + k_] = cand_;                                           \
  }                                                                           \
} while (0)

#define PROCESS16(buf, blk) do {                                              \
  _Pragma("unroll")                                                           \
  for (int j_ = 0; j_ < 4; ++j_) {                                            \
    const int4 c4_ = ordv[(blk) * 4 + j_];                                    \
    STEP(c4_.x, buf[4*j_+0]);                                                 \
    STEP(c4_.y, buf[4*j_+1]);                                                 \
    STEP(c4_.z, buf[4*j_+2]);                                                 \
    STEP(c4_.w, buf[4*j_+3]);                                                 \
  }                                                                           \
} while (0)

__global__ __launch_bounds__(256, 1) void sort_scan(
    const float* __restrict__ scores, const float* __restrict__ sthr_p,
    const uint32_t* __restrict__ ov, int* __restrict__ match)
{
  __shared__ float sk[N_];
  __shared__ __align__(16) int sv[N_];
  __shared__ __align__(16) int match_s[N_];
  __shared__ uint32_t sup0[NW];

  const int bc = blockIdx.x;                // b*CLS + c
  const int b  = bc / CLS;
  const float sthr = sthr_p[0];
  const float* s = scores + (size_t)bc * N_;

  // ---- phase 1: load + suppressed0 ballot + init ----
  for (int i = threadIdx.x; i < N_; i += 256) {
    const float v = s[i];
    sk[i] = v;
    sv[i] = i;
    match_s[i] = -1;
    const unsigned long long bal = __ballot(v <= sthr);
    if ((threadIdx.x & 63) == 0) {          // i here is a multiple of 64
      sup0[(i >> 5)]     = (uint32_t)bal;
      sup0[(i >> 5) + 1] = (uint32_t)(bal >> 32);
    }
  }
  // bitonic sort: descending by score, ties -> smaller index first (stable)
  for (int size = 2; size <= N_; size <<= 1) {
    for (int stride = size >> 1; stride > 0; stride >>= 1) {
      __syncthreads();
      for (int t = threadIdx.x; t < N_ / 2; t += 256) {
        const int pos = 2 * t - (t & (stride - 1));
        const bool desc = ((t & (size >> 1)) == 0);
        const float ka = sk[pos], kb = sk[pos + stride];
        const int   va = sv[pos], vb = sv[pos + stride];
        const bool aBeforeB = (ka > kb) || (ka == kb && va < vb);
        if (desc != aBeforeB) {
          sk[pos] = kb; sk[pos + stride] = ka;
          sv[pos] = vb; sv[pos + stride] = va;
        }
      }
    }
  }
  __syncthreads();

  // ---- phase 2: greedy scan on wave 0 ----
  if (threadIdx.x < 64) {
    const int l  = threadIdx.x;             // word index 0..63
    const int l4 = l << 2;                  // byte offset of word l in a row
    const uint32_t* basep = ov + (size_t)b * N_ * NW;  // wave-uniform SGPR base
    const int4* ordv = (const int4*)sv;
    uint32_t sup = sup0[l];

    uint32_t bA[16], bB[16], bC[16];        // triple buffer, 48 VGPRs
    ISSUE16(bA, 0);
    ISSUE16(bB, 1);
    ISSUE16(bC, 2);
    for (int g = 0; g < 42; ++g) {          // blocks 0..125
      const int t0 = 3 * g;
      WAITV(32); PROCESS16(bA, t0);     if (t0 + 3 < 128) ISSUE16(bA, t0 + 3);
      WAITV(32); PROCESS16(bB, t0 + 1); if (t0 + 4 < 128) ISSUE16(bB, t0 + 4);
      WAITV(32); PROCESS16(bC, t0 + 2); if (t0 + 5 < 128) ISSUE16(bC, t0 + 5);
    }
    WAITV(16); PROCESS16(bA, 126);          // 126 % 3 == 0 -> bA
    WAITV(0);  PROCESS16(bB, 127);          // 127 % 3 == 1 -> bB
  }
  __syncthreads();

  // ---- phase 3: coalesced writeout ----
  int4* mg = (int4*)(match + (size_t)bc * N_);
  const int4* ms = (const int4*)match_s;
  for (int i = threadIdx.x; i < N_ / 4; i += 256) mg[i] = ms[i];
}

extern "C" void kernel_launch(void* const* d_in, const int* in_sizes, int n_in,
                              void* d_out, int out_size, void* d_ws, size_t ws_size,
                              hipStream_t stream)
{
  const float4* boxes  = (const float4*)d_in[0];   // [B,N,4] f32
  const float*  scores = (const float*)d_in[1];    // [B,C,N] f32
  const float*  iouthr = (const float*)d_in[2];    // [1]
  const float*  scthr  = (const float*)d_in[3];    // [1]
  int* match = (int*)d_out;                        // [B,C,N] int32

  uint32_t* ov = (uint32_t*)d_ws;                  // 2 MiB mask

  build_mask<<<dim3(B_ * (N_ / 32)), dim3(256), 0, stream>>>(boxes, iouthr, ov);
  sort_scan <<<dim3(B_ * CLS),       dim3(256), 0, stream>>>(scores, scthr, ov, match);
}

// Round 6
// 227.818 us; speedup vs baseline: 4.1569x; 1.3898x over previous
//
#include <hip/hip_runtime.h>
#include <stdint.h>

#define N_   2048      // boxes per batch
#define NW   64        // u32 words per mask row (N_/32)
#define CLS  4
#define B_   4

// ---------------- Kernel A: pairwise IoU -> bitmask (ballot form) ----------
// ov[b][i][w] bit k set iff IoU(box i, box w*32+k) > thr (symmetric, diag set)
// One wave per row-chunk: lane j tests IoU(row, g*64+j); __ballot packs 64
// predicates; word-select leaves lane j holding word j -> coalesced row store.
// LDS reads are lane-contiguous float4 (conflict-free), bi is a broadcast.
__global__ __launch_bounds__(256) void build_mask(
    const float4* __restrict__ boxes, const float* __restrict__ thr_p,
    uint32_t* __restrict__ ov)
{
  __shared__ float4 sb[N_];                 // 32 KiB: all boxes of this batch
  const int b    = blockIdx.x >> 6;         // 64 tiles per batch
  const int tile = blockIdx.x & 63;         // 32 rows per tile
  const float thr = thr_p[0];
  for (int i = threadIdx.x; i < N_; i += 256) sb[i] = boxes[b * N_ + i];
  __syncthreads();
  const int wv = threadIdx.x >> 6;          // wave 0..3
  const int ln = threadIdx.x & 63;
  #pragma unroll 2
  for (int rr = 0; rr < 8; ++rr) {          // 8 rows per wave
    const int r = tile * 32 + wv * 8 + rr;
    const float4 bi = sb[r];
    const float areai = (bi.z - bi.x) * (bi.w - bi.y);
    uint32_t myw = 0u;
    #pragma unroll 4
    for (int g = 0; g < 32; ++g) {          // 64 boxes per group
      const float4 bj = sb[g * 64 + ln];
      const float xx1 = fmaxf(bi.x, bj.x);
      const float yy1 = fmaxf(bi.y, bj.y);
      const float xx2 = fminf(bi.z, bj.z);
      const float yy2 = fminf(bi.w, bj.w);
      const float iw = fmaxf(xx2 - xx1, 0.0f);
      const float ih = fmaxf(yy2 - yy1, 0.0f);
      const float inter = iw * ih;
      const float areaj = (bj.z - bj.x) * (bj.w - bj.y);
      const float uni = fmaxf(areai + areaj - inter, 1e-6f);
      const unsigned long long bal = __ballot(inter / uni > thr); // exact ref op order
      const uint32_t lo = (uint32_t)bal, hi = (uint32_t)(bal >> 32);
      if ((ln >> 1) == g) myw = (ln & 1) ? hi : lo;
    }
    ov[((size_t)(b * N_ + r)) * NW + ln] = myw;   // 256B coalesced row store
  }
}

// ---------------- Kernel B: sort + asm greedy scan + parallel extraction ----
// Scan (wave 0, ONE asm volatile block): lane l owns leader-bitmap word l.
// Candidate c suppressed <=> (row_c & lead) != 0  (M symmetric, diag set);
// else lead |= bit(c). Depth-3 pipeline, 16 rows/block, hand-counted vmcnt.
// Register map (hard clobbers): v32 lane, v33 l*4, v34 lead, v35-38 temps,
// v39 cand LDS addr, v40 const 1, C0 v44-59, C1 v60-75, C2 v76-91,
// R0 v92-107, R1 v108-123, R2 v124-139.

#define S_(r,c) \
  "v_and_b32 v35, v" #r ", v34\n\t"            \
  "v_cmp_ne_u32 vcc, 0, v35\n\t"               \
  "s_cmp_lg_u64 vcc, 0\n\t"                    \
  "s_cselect_b32 s40, 0, -1\n\t"               \
  "v_bfe_u32 v36, v" #c ", 5, 6\n\t"           \
  "v_cmp_eq_u32 s[42:43], v36, v32\n\t"        \
  "v_and_b32 v37, 31, v" #c "\n\t"             \
  "v_lshlrev_b32 v37, v37, v40\n\t"            \
  "v_cndmask_b32 v37, 0, v37, s[42:43]\n\t"    \
  "v_and_b32 v37, s40, v37\n\t"                \
  "v_or_b32 v34, v34, v37\n\t"

#define F_(r,c) \
  "v_lshlrev_b32 v38, 8, v" #c "\n\t"          \
  "v_add_u32 v38, v38, v33\n\t"                \
  "global_load_dword v" #r ", v38, %[B]\n\t"

#define PROC_A S_(92,44) S_(93,45) S_(94,46) S_(95,47) S_(96,48) S_(97,49) S_(98,50) S_(99,51) S_(100,52) S_(101,53) S_(102,54) S_(103,55) S_(104,56) S_(105,57) S_(106,58) S_(107,59)
#define PROC_B S_(108,60) S_(109,61) S_(110,62) S_(111,63) S_(112,64) S_(113,65) S_(114,66) S_(115,67) S_(116,68) S_(117,69) S_(118,70) S_(119,71) S_(120,72) S_(121,73) S_(122,74) S_(123,75)
#define PROC_C S_(124,76) S_(125,77) S_(126,78) S_(127,79) S_(128,80) S_(129,81) S_(130,82) S_(131,83) S_(132,84) S_(133,85) S_(134,86) S_(135,87) S_(136,88) S_(137,89) S_(138,90) S_(139,91)

#define REF_A F_(92,44) F_(93,45) F_(94,46) F_(95,47) F_(96,48) F_(97,49) F_(98,50) F_(99,51) F_(100,52) F_(101,53) F_(102,54) F_(103,55) F_(104,56) F_(105,57) F_(106,58) F_(107,59)
#define REF_B F_(108,60) F_(109,61) F_(110,62) F_(111,63) F_(112,64) F_(113,65) F_(114,66) F_(115,67) F_(116,68) F_(117,69) F_(118,70) F_(119,71) F_(120,72) F_(121,73) F_(122,74) F_(123,75)
#define REF_C F_(124,76) F_(125,77) F_(126,78) F_(127,79) F_(128,80) F_(129,81) F_(130,82) F_(131,83) F_(132,84) F_(133,85) F_(136,88) F_(134,86) F_(135,87) F_(137,89) F_(138,90) F_(139,91)

#define DSR_A \
  "ds_read_b128 v[44:47], v39\n\t"             \
  "ds_read_b128 v[48:51], v39 offset:16\n\t"   \
  "ds_read_b128 v[52:55], v39 offset:32\n\t"   \
  "ds_read_b128 v[56:59], v39 offset:48\n\t"   \
  "v_add_u32 v39, 64, v39\n\t"                 \
  "s_waitcnt lgkmcnt(0)\n\t"
#define DSR_B \
  "ds_read_b128 v[60:63], v39\n\t"             \
  "ds_read_b128 v[64:67], v39 offset:16\n\t"   \
  "ds_read_b128 v[68:71], v39 offset:32\n\t"   \
  "ds_read_b128 v[72:75], v39 offset:48\n\t"   \
  "v_add_u32 v39, 64, v39\n\t"                 \
  "s_waitcnt lgkmcnt(0)\n\t"
#define DSR_C \
  "ds_read_b128 v[76:79], v39\n\t"             \
  "ds_read_b128 v[80:83], v39 offset:16\n\t"   \
  "ds_read_b128 v[84:87], v39 offset:32\n\t"   \
  "ds_read_b128 v[88:91], v39 offset:48\n\t"   \
  "v_add_u32 v39, 64, v39\n\t"                 \
  "s_waitcnt lgkmcnt(0)\n\t"

__global__ __launch_bounds__(256, 1) void sort_scan(
    const float* __restrict__ scores, const float* __restrict__ sthr_p,
    const uint32_t* __restrict__ ov, int* __restrict__ match)
{
  __shared__ float sk[N_];
  __shared__ __align__(16) int sv[N_];
  __shared__ int rk[N_];
  __shared__ uint32_t sup0[NW];
  __shared__ uint32_t lead_s[NW];
  __shared__ int cnt_s;

  const int bc = blockIdx.x;                // b*CLS + c
  const int b  = bc / CLS;
  const float sthr = sthr_p[0];
  const float* s = scores + (size_t)bc * N_;

  // ---- phase 1: load + suppressed0 ballot ----
  for (int i = threadIdx.x; i < N_; i += 256) {
    const float v = s[i];
    sk[i] = v;
    sv[i] = i;
    const unsigned long long bal = __ballot(v <= sthr);
    if ((threadIdx.x & 63) == 0) {          // i here is a multiple of 64
      sup0[(i >> 5)]     = (uint32_t)bal;
      sup0[(i >> 5) + 1] = (uint32_t)(bal >> 32);
    }
  }
  // bitonic sort: descending by score, ties -> smaller index first (stable)
  for (int size = 2; size <= N_; size <<= 1) {
    for (int stride = size >> 1; stride > 0; stride >>= 1) {
      __syncthreads();
      for (int t = threadIdx.x; t < N_ / 2; t += 256) {
        const int pos = 2 * t - (t & (stride - 1));
        const bool desc = ((t & (size >> 1)) == 0);
        const float ka = sk[pos], kb = sk[pos + stride];
        const int   va = sv[pos], vb = sv[pos + stride];
        const bool aBeforeB = (ka > kb) || (ka == kb && va < vb);
        if (desc != aBeforeB) {
          sk[pos] = kb; sk[pos + stride] = ka;
          sv[pos] = vb; sv[pos + stride] = va;
        }
      }
    }
  }
  __syncthreads();

  // ---- rank array + above-threshold count ----
  for (int i = threadIdx.x; i < N_; i += 256) rk[sv[i]] = i;
  if (threadIdx.x == 0) {
    int c = 0;
    for (int w = 0; w < NW; ++w) c += __popc(sup0[w]);
    cnt_s = N_ - c;                         // # of score>sthr boxes
  }
  __syncthreads();
  // pad tail (below-thr region) with a duplicate of the last real candidate:
  // re-processing a candidate is idempotent for the leader bitmap.
  {
    const int cnt = cnt_s;
    if (cnt > 0)
      for (int i = cnt + threadIdx.x; i < N_; i += 256) sv[i] = sv[cnt - 1];
  }
  __syncthreads();

  // ---- phase 2: greedy scan, wave 0, one asm block ----
  if (threadIdx.x < 64) {
    const int l  = threadIdx.x;
    const int l4 = l << 2;
    const uint32_t cb = (uint32_t)(uintptr_t)(&sv[0]);   // LDS byte offset
    const uint32_t* rowb = ov + (size_t)b * N_ * NW;
    uint32_t vlead;
    asm volatile(
      "s_waitcnt vmcnt(0) lgkmcnt(0)\n\t"
      "v_mov_b32 v32, %[LN]\n\t"
      "v_mov_b32 v33, %[L4]\n\t"
      "v_mov_b32 v34, 0\n\t"
      "v_mov_b32 v39, %[CB]\n\t"
      "v_mov_b32 v40, 1\n\t"
      DSR_A REF_A
      DSR_B REF_B
      DSR_C REF_C
      "s_mov_b32 s41, 41\n\t"
      "LSCAN%=:\n\t"
      "s_waitcnt vmcnt(32)\n\t" PROC_A DSR_A REF_A
      "s_waitcnt vmcnt(32)\n\t" PROC_B DSR_B REF_B
      "s_waitcnt vmcnt(32)\n\t" PROC_C DSR_C REF_C
      "s_sub_u32 s41, s41, 1\n\t"
      "s_cmp_lg_u32 s41, 0\n\t"
      "s_cbranch_scc1 LSCAN%=\n\t"
      "s_waitcnt vmcnt(32)\n\t" PROC_A DSR_A REF_A
      "s_waitcnt vmcnt(32)\n\t" PROC_B DSR_B REF_B
      "s_waitcnt vmcnt(32)\n\t" PROC_C
      "s_waitcnt vmcnt(16)\n\t" PROC_A
      "s_waitcnt vmcnt(0)\n\t"  PROC_B
      "v_mov_b32 %[LD], v34\n\t"
      : [LD] "=v"(vlead)
      : [LN] "v"(l), [L4] "v"(l4), [CB] "v"(cb), [B] "s"(rowb)
      : "memory", "vcc", "scc", "s40", "s41", "s42", "s43",
        "v32","v33","v34","v35","v36","v37","v38","v39","v40","v41","v42","v43",
        "v44","v45","v46","v47","v48","v49","v50","v51","v52","v53","v54","v55",
        "v56","v57","v58","v59","v60","v61","v62","v63","v64","v65","v66","v67",
        "v68","v69","v70","v71","v72","v73","v74","v75","v76","v77","v78","v79",
        "v80","v81","v82","v83","v84","v85","v86","v87","v88","v89","v90","v91",
        "v92","v93","v94","v95","v96","v97","v98","v99","v100","v101","v102","v103",
        "v104","v105","v106","v107","v108","v109","v110","v111","v112","v113","v114","v115",
        "v116","v117","v118","v119","v120","v121","v122","v123","v124","v125","v126","v127",
        "v128","v129","v130","v131","v132","v133","v134","v135","v136","v137","v138","v139");
    lead_s[l] = vlead;
  }
  __syncthreads();

  // ---- phase 3: parallel extraction ----
  // match[n] = original index of the min-rank leader overlapping n (== greedy
  // claimant), or -1 if score<=sthr. Self-bit guarantees a hit for kept boxes.
  const uint32_t* Mb = ov + (size_t)b * N_ * NW;
  for (int k = 0; k < 8; ++k) {
    const int n = (k << 8) + threadIdx.x;
    int res = -1;
    if (!((sup0[n >> 5] >> (n & 31)) & 1u)) {
      const uint4* r4 = (const uint4*)(Mb + (size_t)n * NW);
      const uint4* g4 = (const uint4*)lead_s;
      int best = 1 << 30;
      #pragma unroll
      for (int j = 0; j < 16; ++j) {
        const uint4 a = r4[j];
        const uint4 g = g4[j];
        uint32_t w0 = a.x & g.x, w1 = a.y & g.y, w2 = a.z & g.z, w3 = a.w & g.w;
        while (w0) { const int bb = __ffs(w0) - 1; w0 &= w0 - 1;
          const int jj = (j << 7) + bb;      const int r = rk[jj];
          if (r < best) { best = r; res = jj; } }
        while (w1) { const int bb = __ffs(w1) - 1; w1 &= w1 - 1;
          const int jj = (j << 7) + 32 + bb; const int r = rk[jj];
          if (r < best) { best = r; res = jj; } }
        while (w2) { const int bb = __ffs(w2) - 1; w2 &= w2 - 1;
          const int jj = (j << 7) + 64 + bb; const int r = rk[jj];
          if (r < best) { best = r; res = jj; } }
        while (w3) { const int bb = __ffs(w3) - 1; w3 &= w3 - 1;
          const int jj = (j << 7) + 96 + bb; const int r = rk[jj];
          if (r < best) { best = r; res = jj; } }
      }
    }
    match[(size_t)bc * N_ + n] = res;
  }
}

extern "C" void kernel_launch(void* const* d_in, const int* in_sizes, int n_in,
                              void* d_out, int out_size, void* d_ws, size_t ws_size,
                              hipStream_t stream)
{
  const float4* boxes  = (const float4*)d_in[0];   // [B,N,4] f32
  const float*  scores = (const float*)d_in[1];    // [B,C,N] f32
  const float*  iouthr = (const float*)d_in[2];    // [1]
  const float*  scthr  = (const float*)d_in[3];    // [1]
  int* match = (int*)d_out;                        // [B,C,N] int32

  uint32_t* ov = (uint32_t*)d_ws;                  // 2 MiB mask

  build_mask<<<dim3(B_ * 64),  dim3(256), 0, stream>>>(boxes, iouthr, ov);
  sort_scan <<<dim3(B_ * CLS), dim3(256), 0, stream>>>(scores, scthr, ov, match);
}

// Round 7
// 203.503 us; speedup vs baseline: 4.6535x; 1.1195x over previous
//
#include <hip/hip_runtime.h>
#include <stdint.h>

#define N_   2048      // boxes per batch
#define NW   64        // u32 words per mask row (N_/32)
#define CLS  4
#define B_   4
#define ORD_STRIDE (N_ + 64)   // sorted order padded for scan staging overshoot

// ============================ Kernel 1 ======================================
// blocks 0..255   : mask role — pairwise IoU -> bitmask (loop-inverted ballot)
// blocks 256..271 : sort role — per-(b,c) packed-u64 bitonic argsort
__global__ __launch_bounds__(256) void mask_or_sort(
    const float4* __restrict__ boxes, const float* __restrict__ thr_p,
    const float* __restrict__ scores, const float* __restrict__ sthr_p,
    uint32_t* __restrict__ ov, int* __restrict__ order,
    int* __restrict__ rk, uint32_t* __restrict__ sup0ws)
{
  __shared__ __align__(16) unsigned char lds_raw[32768];
  __shared__ uint32_t sup_l[NW];
  __shared__ int cnt_s;

  if (blockIdx.x < 256) {
    // ---------------- mask role ----------------
    float4* sb = (float4*)lds_raw;
    const int b    = blockIdx.x >> 6;       // 64 tiles per batch
    const int tile = blockIdx.x & 63;       // 32 rows per tile
    const float thr = thr_p[0];
    for (int i = threadIdx.x; i < N_; i += 256) sb[i] = boxes[b * N_ + i];
    __syncthreads();
    const int wv = threadIdx.x >> 6;        // wave 0..3
    const int ln = threadIdx.x & 63;
    const int r0 = tile * 32 + wv * 8;      // 8 rows per wave
    float4 bi[8]; float areai[8];
    #pragma unroll
    for (int rr = 0; rr < 8; ++rr) {
      bi[rr] = sb[r0 + rr];
      areai[rr] = (bi[rr].z - bi[rr].x) * (bi[rr].w - bi[rr].y);
    }
    uint32_t myw[8] = {0, 0, 0, 0, 0, 0, 0, 0};
    for (int g = 0; g < 32; ++g) {          // 64 boxes per group
      const float4 bj = sb[g * 64 + ln];
      const float areaj = (bj.z - bj.x) * (bj.w - bj.y);
      const bool sel = ((ln >> 1) == g);
      const bool hi  = (ln & 1);
      #pragma unroll
      for (int rr = 0; rr < 8; ++rr) {      // 8 independent IoU chains per load
        const float xx1 = fmaxf(bi[rr].x, bj.x);
        const float yy1 = fmaxf(bi[rr].y, bj.y);
        const float xx2 = fminf(bi[rr].z, bj.z);
        const float yy2 = fminf(bi[rr].w, bj.w);
        const float iw = fmaxf(xx2 - xx1, 0.0f);
        const float ih = fmaxf(yy2 - yy1, 0.0f);
        const float inter = iw * ih;
        const float uni = fmaxf(areai[rr] + areaj - inter, 1e-6f);
        const unsigned long long bal = __ballot(inter / uni > thr); // ref op order
        const uint32_t w = hi ? (uint32_t)(bal >> 32) : (uint32_t)bal;
        if (sel) myw[rr] = w;
      }
    }
    #pragma unroll
    for (int rr = 0; rr < 8; ++rr)
      ov[((size_t)(b * N_ + r0 + rr)) * NW + ln] = myw[rr]; // 256B coalesced
  } else {
    // ---------------- sort role ----------------
    unsigned long long* sp = (unsigned long long*)lds_raw;  // 16 KiB
    const int bc = blockIdx.x - 256;        // b*CLS + c
    const float sthr = sthr_p[0];
    const float* s = scores + (size_t)bc * N_;
    for (int i = threadIdx.x; i < N_; i += 256) {
      const float v = s[i];
      uint32_t u = __float_as_uint(v);
      u = (u >> 31) ? ~u : (u | 0x80000000u);          // monotone float->uint
      sp[i] = ((unsigned long long)u << 32) | (uint32_t)(~(uint32_t)i);
      const unsigned long long bal = __ballot(v <= sthr);
      if ((threadIdx.x & 63) == 0) {        // i is a multiple of 64 here
        sup_l[(i >> 5)]     = (uint32_t)bal;
        sup_l[(i >> 5) + 1] = (uint32_t)(bal >> 32);
      }
    }
    // bitonic: descending by packed u64 => score desc, ties index asc (exact)
    for (int size = 2; size <= N_; size <<= 1) {
      for (int stride = size >> 1; stride > 0; stride >>= 1) {
        __syncthreads();
        for (int t = threadIdx.x; t < N_ / 2; t += 256) {
          const int pos = 2 * t - (t & (stride - 1));
          const bool desc = ((t & (size >> 1)) == 0);
          const unsigned long long a = sp[pos], c = sp[pos + stride];
          if (desc != (a > c)) { sp[pos] = c; sp[pos + stride] = a; }
        }
      }
    }
    __syncthreads();
    if (threadIdx.x == 0) {
      int c2 = 0;
      for (int w = 0; w < NW; ++w) c2 += __popc(sup_l[w]);
      cnt_s = N_ - c2;                      // # of score>sthr boxes
    }
    __syncthreads();
    const int cnt = cnt_s;
    const int last = (cnt > 0) ? (int)~(uint32_t)sp[cnt - 1] : 0;
    int* ord_o = order + (size_t)bc * ORD_STRIDE;
    int* rk_o  = rk    + (size_t)bc * N_;
    for (int i = threadIdx.x; i < N_; i += 256) {
      const int idx = (int)~(uint32_t)sp[i];
      // below-thr tail replaced by dup of last real candidate (idempotent)
      ord_o[i] = (i < cnt || cnt == 0) ? idx : last;
      rk_o[idx] = i;                        // rank BEFORE padding (as validated)
    }
    for (int i = N_ + threadIdx.x; i < ORD_STRIDE; i += 256) ord_o[i] = last;
    if (threadIdx.x < NW) sup0ws[bc * NW + threadIdx.x] = sup_l[threadIdx.x];
  }
}

// ============================ Kernel 2 ======================================
// wave 0: asm greedy scan -> leader bitmap. Lane l owns lead word l (v34).
// Serial chain per candidate is 6 ops; owner-bit (MB_) and row refill (RF_)
// are precomputed/interleaved off the chain. Depth-3 row pipeline (48 loads
// in flight, vmcnt(32) waits); candidate staging regs v140-155 loaded one
// phase ahead via ds_read_b128. Then all 256 threads do parallel extraction.
//
// Register map (hard clobbers): v32 lane, v33 l*4, v34 lead, v35-38 temps,
// v39 LDS cand ptr, v40 const 1, bits A/B/C v44-59/60-75/76-91,
// rows A/B/C v92-107/108-123/124-139, staging v140-155.

#define S6_(rw,bt) \
  "v_and_b32 v35, v" #rw ", v34\n\t"           \
  "v_cmp_ne_u32 vcc, 0, v35\n\t"               \
  "s_cmp_lg_u64 vcc, 0\n\t"                    \
  "s_cselect_b32 s40, 0, -1\n\t"               \
  "v_and_b32 v37, s40, v" #bt "\n\t"           \
  "v_or_b32 v34, v34, v37\n\t"

#define RF_(rw,st) \
  "v_lshlrev_b32 v38, 8, v" #st "\n\t"         \
  "v_add_u32 v38, v38, v33\n\t"                \
  "global_load_dword v" #rw ", v38, %[B]\n\t"

#define MB_(bt,st) \
  "v_bfe_u32 v36, v" #st ", 5, 6\n\t"          \
  "v_cmp_eq_u32 s[42:43], v36, v32\n\t"        \
  "v_cndmask_b32 v37, 0, v40, s[42:43]\n\t"    \
  "v_lshlrev_b32 v" #bt ", v" #st ", v37\n\t"

#define CAND(rw,bt,st) S6_(rw,bt) RF_(rw,st) MB_(bt,st)
#define CP(rw,bt,st)   RF_(rw,st) MB_(bt,st)

#define DSR4 \
  "ds_read_b128 v[140:143], v39\n\t"           \
  "ds_read_b128 v[144:147], v39 offset:16\n\t" \
  "ds_read_b128 v[148:151], v39 offset:32\n\t" \
  "ds_read_b128 v[152:155], v39 offset:48\n\t" \
  "v_add_u32 v39, 64, v39\n\t"

#define PH_HDR "s_waitcnt vmcnt(32)\n\t" "s_waitcnt lgkmcnt(0)\n\t"

#define PH_A PH_HDR \
  CAND(92,44,140)  CAND(93,45,141)  CAND(94,46,142)  CAND(95,47,143)  \
  CAND(96,48,144)  CAND(97,49,145)  CAND(98,50,146)  CAND(99,51,147)  \
  CAND(100,52,148) CAND(101,53,149) CAND(102,54,150) CAND(103,55,151) \
  CAND(104,56,152) CAND(105,57,153) CAND(106,58,154) CAND(107,59,155) DSR4
#define PH_B PH_HDR \
  CAND(108,60,140) CAND(109,61,141) CAND(110,62,142) CAND(111,63,143) \
  CAND(112,64,144) CAND(113,65,145) CAND(114,66,146) CAND(115,67,147) \
  CAND(116,68,148) CAND(117,69,149) CAND(118,70,150) CAND(119,71,151) \
  CAND(120,72,152) CAND(121,73,153) CAND(122,74,154) CAND(123,75,155) DSR4
#define PH_C PH_HDR \
  CAND(124,76,140) CAND(125,77,141) CAND(126,78,142) CAND(127,79,143) \
  CAND(128,80,144) CAND(129,81,145) CAND(130,82,146) CAND(131,83,147) \
  CAND(132,84,148) CAND(133,85,149) CAND(134,86,150) CAND(135,87,151) \
  CAND(136,88,152) CAND(137,89,153) CAND(138,90,154) CAND(139,91,155) DSR4

#define PRO_A \
  CP(92,44,140)  CP(93,45,141)  CP(94,46,142)  CP(95,47,143)  \
  CP(96,48,144)  CP(97,49,145)  CP(98,50,146)  CP(99,51,147)  \
  CP(100,52,148) CP(101,53,149) CP(102,54,150) CP(103,55,151) \
  CP(104,56,152) CP(105,57,153) CP(106,58,154) CP(107,59,155)
#define PRO_B \
  CP(108,60,140) CP(109,61,141) CP(110,62,142) CP(111,63,143) \
  CP(112,64,144) CP(113,65,145) CP(114,66,146) CP(115,67,147) \
  CP(116,68,148) CP(117,69,149) CP(118,70,150) CP(119,71,151) \
  CP(120,72,152) CP(121,73,153) CP(122,74,154) CP(123,75,155)
#define PRO_C \
  CP(124,76,140) CP(125,77,141) CP(126,78,142) CP(127,79,143) \
  CP(128,80,144) CP(129,81,145) CP(130,82,146) CP(131,83,147) \
  CP(132,84,148) CP(133,85,149) CP(134,86,150) CP(135,87,151) \
  CP(136,88,152) CP(137,89,153) CP(138,90,154) CP(139,91,155)

__global__ __launch_bounds__(256, 1) void scan_extract(
    const uint32_t* __restrict__ ov, const int* __restrict__ order,
    const int* __restrict__ rk, const uint32_t* __restrict__ sup0ws,
    int* __restrict__ match)
{
  __shared__ __align__(16) int sv[ORD_STRIDE];
  __shared__ __align__(16) int rk_s[N_];
  __shared__ uint32_t lead_s[NW];
  __shared__ uint32_t sup_s[NW];

  const int bc = blockIdx.x;                // b*CLS + c
  const int b  = bc / CLS;

  // ---- load sorted order / rank / sup0 into LDS (coalesced) ----
  {
    const int4* osrc = (const int4*)(order + (size_t)bc * ORD_STRIDE);
    int4* odst = (int4*)sv;
    for (int i = threadIdx.x; i < ORD_STRIDE / 4; i += 256) odst[i] = osrc[i];
    const int4* rsrc = (const int4*)(rk + (size_t)bc * N_);
    int4* rdst = (int4*)rk_s;
    for (int i = threadIdx.x; i < N_ / 4; i += 256) rdst[i] = rsrc[i];
    if (threadIdx.x < NW) sup_s[threadIdx.x] = sup0ws[bc * NW + threadIdx.x];
  }
  __syncthreads();

  // ---- greedy scan, wave 0, one asm block ----
  if (threadIdx.x < 64) {
    const int l  = threadIdx.x;
    const int l4 = l << 2;
    const uint32_t cb = (uint32_t)(uintptr_t)(&sv[0]);   // LDS byte offset
    const uint32_t* rowb = ov + (size_t)b * N_ * NW;
    uint32_t vlead;
    asm volatile(
      "s_waitcnt vmcnt(0) lgkmcnt(0)\n\t"
      "v_mov_b32 v32, %[LN]\n\t"
      "v_mov_b32 v33, %[L4]\n\t"
      "v_mov_b32 v34, 0\n\t"
      "v_mov_b32 v39, %[CB]\n\t"
      "v_mov_b32 v40, 1\n\t"
      DSR4 "s_waitcnt lgkmcnt(0)\n\t" PRO_A
      DSR4 "s_waitcnt lgkmcnt(0)\n\t" PRO_B
      DSR4 "s_waitcnt lgkmcnt(0)\n\t" PRO_C
      DSR4
      "s_mov_b32 s41, 42\n\t"
      "LSCAN%=:\n\t"
      PH_A PH_B PH_C
      "s_sub_u32 s41, s41, 1\n\t"
      "s_cmp_lg_u32 s41, 0\n\t"
      "s_cbranch_scc1 LSCAN%=\n\t"
      PH_A PH_B
      "s_waitcnt vmcnt(0) lgkmcnt(0)\n\t"
      "v_mov_b32 %[LD], v34\n\t"
      : [LD] "=v"(vlead)
      : [LN] "v"(l), [L4] "v"(l4), [CB] "v"(cb), [B] "s"(rowb)
      : "memory", "vcc", "scc", "s40", "s41", "s42", "s43",
        "v32","v33","v34","v35","v36","v37","v38","v39","v40","v41","v42","v43",
        "v44","v45","v46","v47","v48","v49","v50","v51","v52","v53","v54","v55",
        "v56","v57","v58","v59","v60","v61","v62","v63","v64","v65","v66","v67",
        "v68","v69","v70","v71","v72","v73","v74","v75","v76","v77","v78","v79",
        "v80","v81","v82","v83","v84","v85","v86","v87","v88","v89","v90","v91",
        "v92","v93","v94","v95","v96","v97","v98","v99","v100","v101","v102","v103",
        "v104","v105","v106","v107","v108","v109","v110","v111","v112","v113","v114","v115",
        "v116","v117","v118","v119","v120","v121","v122","v123","v124","v125","v126","v127",
        "v128","v129","v130","v131","v132","v133","v134","v135","v136","v137","v138","v139",
        "v140","v141","v142","v143","v144","v145","v146","v147","v148","v149","v150","v151",
        "v152","v153","v154","v155");
    lead_s[l] = vlead;
  }
  __syncthreads();

  // ---- parallel extraction ----
  // match[n] = original index of the min-rank leader overlapping n (== greedy
  // claimant), or -1 if score<=sthr. Self-bit guarantees a hit for kept boxes.
  const uint32_t* Mb = ov + (size_t)b * N_ * NW;
  for (int k = 0; k < 8; ++k) {
    const int n = (k << 8) + threadIdx.x;
    int res = -1;
    if (!((sup_s[n >> 5] >> (n & 31)) & 1u)) {
      const uint4* r4 = (const uint4*)(Mb + (size_t)n * NW);
      const uint4* g4 = (const uint4*)lead_s;
      int best = 1 << 30;
      #pragma unroll
      for (int j = 0; j < 16; ++j) {
        const uint4 a = r4[j];
        const uint4 g = g4[j];
        uint32_t w0 = a.x & g.x, w1 = a.y & g.y, w2 = a.z & g.z, w3 = a.w & g.w;
        while (w0) { const int bb = __ffs(w0) - 1; w0 &= w0 - 1;
          const int jj = (j << 7) + bb;      const int r = rk_s[jj];
          if (r < best) { best = r; res = jj; } }
        while (w1) { const int bb = __ffs(w1) - 1; w1 &= w1 - 1;
          const int jj = (j << 7) + 32 + bb; const int r = rk_s[jj];
          if (r < best) { best = r; res = jj; } }
        while (w2) { const int bb = __ffs(w2) - 1; w2 &= w2 - 1;
          const int jj = (j << 7) + 64 + bb; const int r = rk_s[jj];
          if (r < best) { best = r; res = jj; } }
        while (w3) { const int bb = __ffs(w3) - 1; w3 &= w3 - 1;
          const int jj = (j << 7) + 96 + bb; const int r = rk_s[jj];
          if (r < best) { best = r; res = jj; } }
      }
    }
    match[(size_t)bc * N_ + n] = res;
  }
}

extern "C" void kernel_launch(void* const* d_in, const int* in_sizes, int n_in,
                              void* d_out, int out_size, void* d_ws, size_t ws_size,
                              hipStream_t stream)
{
  const float4* boxes  = (const float4*)d_in[0];   // [B,N,4] f32
  const float*  scores = (const float*)d_in[1];    // [B,C,N] f32
  const float*  iouthr = (const float*)d_in[2];    // [1]
  const float*  scthr  = (const float*)d_in[3];    // [1]
  int* match = (int*)d_out;                        // [B,C,N] int32

  char* ws = (char*)d_ws;
  uint32_t* ov    = (uint32_t*)ws;                                   // 2 MiB
  int*      order = (int*)(ws + (size_t)B_ * N_ * NW * 4);           // 16*2112*4
  int*      rk    = (int*)((char*)order + (size_t)B_ * CLS * ORD_STRIDE * 4);
  uint32_t* sup0  = (uint32_t*)((char*)rk + (size_t)B_ * CLS * N_ * 4);

  mask_or_sort<<<dim3(256 + B_ * CLS), dim3(256), 0, stream>>>(
      boxes, iouthr, scores, scthr, ov, order, rk, sup0);
  scan_extract<<<dim3(B_ * CLS), dim3(256), 0, stream>>>(
      ov, order, rk, sup0, match);
}

// Round 8
// 196.011 us; speedup vs baseline: 4.8314x; 1.0382x over previous
//
#include <hip/hip_runtime.h>
#include <stdint.h>

#define N_   2048      // boxes per batch
#define NW   64        // u32 words per mask row (N_/32)
#define CLS  4
#define B_   4
#define ORD_STRIDE (N_ + 64)   // sorted order padded for scan staging overshoot

// ---------------- Kernel A: pairwise IoU -> bitmask (ballot form) ----------
__global__ __launch_bounds__(256) void build_mask(
    const float4* __restrict__ boxes, const float* __restrict__ thr_p,
    uint32_t* __restrict__ ov)
{
  __shared__ float4 sb[N_];                 // 32 KiB: all boxes of this batch
  const int b    = blockIdx.x >> 6;         // 64 tiles per batch
  const int tile = blockIdx.x & 63;         // 32 rows per tile
  const float thr = thr_p[0];
  for (int i = threadIdx.x; i < N_; i += 256) sb[i] = boxes[b * N_ + i];
  __syncthreads();
  const int wv = threadIdx.x >> 6;          // wave 0..3
  const int ln = threadIdx.x & 63;
  const int r0 = tile * 32 + wv * 8;        // 8 rows per wave
  float4 bi[8]; float areai[8];
  #pragma unroll
  for (int rr = 0; rr < 8; ++rr) {
    bi[rr] = sb[r0 + rr];
    areai[rr] = (bi[rr].z - bi[rr].x) * (bi[rr].w - bi[rr].y);
  }
  uint32_t myw[8] = {0, 0, 0, 0, 0, 0, 0, 0};
  for (int g = 0; g < 32; ++g) {            // 64 boxes per group
    const float4 bj = sb[g * 64 + ln];
    const float areaj = (bj.z - bj.x) * (bj.w - bj.y);
    const bool sel = ((ln >> 1) == g);
    const bool hi  = (ln & 1);
    #pragma unroll
    for (int rr = 0; rr < 8; ++rr) {        // 8 independent IoU chains per load
      const float xx1 = fmaxf(bi[rr].x, bj.x);
      const float yy1 = fmaxf(bi[rr].y, bj.y);
      const float xx2 = fminf(bi[rr].z, bj.z);
      const float yy2 = fminf(bi[rr].w, bj.w);
      const float iw = fmaxf(xx2 - xx1, 0.0f);
      const float ih = fmaxf(yy2 - yy1, 0.0f);
      const float inter = iw * ih;
      const float uni = fmaxf(areai[rr] + areaj - inter, 1e-6f);
      const unsigned long long bal = __ballot(inter / uni > thr); // ref op order
      const uint32_t w = hi ? (uint32_t)(bal >> 32) : (uint32_t)bal;
      if (sel) myw[rr] = w;
    }
  }
  #pragma unroll
  for (int rr = 0; rr < 8; ++rr)
    ov[((size_t)(b * N_ + r0 + rr)) * NW + ln] = myw[rr]; // 256B coalesced
}

// ---------------- Kernel B: per-(b,c) packed-u64 bitonic argsort ------------
__global__ __launch_bounds__(256) void sort_init(
    const float* __restrict__ scores, const float* __restrict__ sthr_p,
    int* __restrict__ order, int* __restrict__ rk, uint32_t* __restrict__ sup0ws)
{
  __shared__ unsigned long long sp[N_];     // 16 KiB
  __shared__ uint32_t sup_l[NW];
  __shared__ int cnt_s;
  const int bc = blockIdx.x;                // b*CLS + c
  const float sthr = sthr_p[0];
  const float* s = scores + (size_t)bc * N_;
  for (int i = threadIdx.x; i < N_; i += 256) {
    const float v = s[i];
    uint32_t u = __float_as_uint(v);
    u = (u >> 31) ? ~u : (u | 0x80000000u); // monotone float->uint
    sp[i] = ((unsigned long long)u << 32) | (uint32_t)(~(uint32_t)i);
    const unsigned long long bal = __ballot(v <= sthr);
    if ((threadIdx.x & 63) == 0) {          // i is a multiple of 64 here
      sup_l[(i >> 5)]     = (uint32_t)bal;
      sup_l[(i >> 5) + 1] = (uint32_t)(bal >> 32);
    }
  }
  // bitonic: descending by packed u64 => score desc, ties index asc (exact)
  for (int size = 2; size <= N_; size <<= 1) {
    for (int stride = size >> 1; stride > 0; stride >>= 1) {
      __syncthreads();
      for (int t = threadIdx.x; t < N_ / 2; t += 256) {
        const int pos = 2 * t - (t & (stride - 1));
        const bool desc = ((t & (size >> 1)) == 0);
        const unsigned long long a = sp[pos], c = sp[pos + stride];
        if (desc != (a > c)) { sp[pos] = c; sp[pos + stride] = a; }
      }
    }
  }
  __syncthreads();
  if (threadIdx.x == 0) {
    int c2 = 0;
    for (int w = 0; w < NW; ++w) c2 += __popc(sup_l[w]);
    cnt_s = N_ - c2;                        // # of score>sthr boxes
  }
  __syncthreads();
  const int cnt = cnt_s;
  const int last = (cnt > 0) ? (int)~(uint32_t)sp[cnt - 1] : 0;
  int* ord_o = order + (size_t)bc * ORD_STRIDE;
  int* rk_o  = rk    + (size_t)bc * N_;
  for (int i = threadIdx.x; i < N_; i += 256) {
    const int idx = (int)~(uint32_t)sp[i];
    ord_o[i] = (i < cnt || cnt == 0) ? idx : last;  // dup-pad tail (idempotent)
    rk_o[idx] = i;
  }
  for (int i = N_ + threadIdx.x; i < ORD_STRIDE; i += 256) ord_o[i] = last;
  if (threadIdx.x < NW) sup0ws[bc * NW + threadIdx.x] = sup_l[threadIdx.x];
}

// ---------------- Kernel C: asm greedy scan -> leader bitmap ----------------
// Lane l owns lead word l (v34). Candidate c suppressed <=> row_c & lead != 0;
// else lead |= ownerbit(c). 128 phases x 16 candidates; depth-3 row pipeline
// (48 loads in flight, vmcnt(32)); staging triple-buffered ONE PHASE AHEAD
// (DSR at phase start -> lgkm wait at next phase start is nearly free).
// Reg map: v32 lane, v33 l*4, v34 lead, v36/v37/v44 temps, v38 addr,
// v39 LDS ptr, v45 const1; bits A/B/C v48-63/64-79/80-95;
// rows A/B/C v96-111/112-127/128-143; stage S0/S1/S2 v144-159/160-175/176-191.

#define C_(r,b,s) \
  "v_and_b32 v36, v" #r ", v34\n\t"              \
  "v_lshlrev_b32 v38, 8, v" #s "\n\t"            \
  "v_cmp_ne_u32 s[46:47], 0, v36\n\t"            \
  "v_add_u32 v38, v38, v33\n\t"                  \
  "v_bfe_u32 v44, v" #s ", 5, 6\n\t"             \
  "s_and_b64 s[46:47], s[46:47], s[46:47]\n\t"   \
  "s_cselect_b32 s40, 0, -1\n\t"                 \
  "global_load_dword v" #r ", v38, %[B]\n\t"     \
  "v_and_b32 v37, s40, v" #b "\n\t"              \
  "v_or_b32 v34, v34, v37\n\t"                   \
  "v_cmp_eq_u32 s[48:49], v44, v32\n\t"          \
  "v_cndmask_b32 v37, 0, v45, s[48:49]\n\t"      \
  "v_lshlrev_b32 v" #b ", v" #s ", v37\n\t"

#define P_(r,b,s) \
  "v_lshlrev_b32 v38, 8, v" #s "\n\t"            \
  "v_add_u32 v38, v38, v33\n\t"                  \
  "global_load_dword v" #r ", v38, %[B]\n\t"     \
  "v_bfe_u32 v44, v" #s ", 5, 6\n\t"             \
  "v_cmp_eq_u32 s[48:49], v44, v32\n\t"          \
  "v_cndmask_b32 v37, 0, v45, s[48:49]\n\t"      \
  "v_lshlrev_b32 v" #b ", v" #s ", v37\n\t"

#define E_(r,b) \
  "v_and_b32 v36, v" #r ", v34\n\t"              \
  "v_cmp_ne_u32 s[46:47], 0, v36\n\t"            \
  "s_and_b64 s[46:47], s[46:47], s[46:47]\n\t"   \
  "s_cselect_b32 s40, 0, -1\n\t"                 \
  "v_and_b32 v37, s40, v" #b "\n\t"              \
  "v_or_b32 v34, v34, v37\n\t"

#define DSR0 \
  "ds_read_b128 v[144:147], v39\n\t"             \
  "ds_read_b128 v[148:151], v39 offset:16\n\t"   \
  "ds_read_b128 v[152:155], v39 offset:32\n\t"   \
  "ds_read_b128 v[156:159], v39 offset:48\n\t"   \
  "v_add_u32 v39, 64, v39\n\t"
#define DSR1 \
  "ds_read_b128 v[160:163], v39\n\t"             \
  "ds_read_b128 v[164:167], v39 offset:16\n\t"   \
  "ds_read_b128 v[168:171], v39 offset:32\n\t"   \
  "ds_read_b128 v[172:175], v39 offset:48\n\t"   \
  "v_add_u32 v39, 64, v39\n\t"
#define DSR2 \
  "ds_read_b128 v[176:179], v39\n\t"             \
  "ds_read_b128 v[180:183], v39 offset:16\n\t"   \
  "ds_read_b128 v[184:187], v39 offset:32\n\t"   \
  "ds_read_b128 v[188:191], v39 offset:48\n\t"   \
  "v_add_u32 v39, 64, v39\n\t"

#define CL_A \
  C_(96,48,144)  C_(97,49,145)  C_(98,50,146)  C_(99,51,147)  \
  C_(100,52,148) C_(101,53,149) C_(102,54,150) C_(103,55,151) \
  C_(104,56,152) C_(105,57,153) C_(106,58,154) C_(107,59,155) \
  C_(108,60,156) C_(109,61,157) C_(110,62,158) C_(111,63,159)
#define CL_B \
  C_(112,64,160) C_(113,65,161) C_(114,66,162) C_(115,67,163) \
  C_(116,68,164) C_(117,69,165) C_(118,70,166) C_(119,71,167) \
  C_(120,72,168) C_(121,73,169) C_(122,74,170) C_(123,75,171) \
  C_(124,76,172) C_(125,77,173) C_(126,78,174) C_(127,79,175)
#define CL_C \
  C_(128,80,176) C_(129,81,177) C_(130,82,178) C_(131,83,179) \
  C_(132,84,180) C_(133,85,181) C_(134,86,182) C_(135,87,183) \
  C_(136,88,184) C_(137,89,185) C_(138,90,186) C_(139,91,187) \
  C_(140,92,188) C_(141,93,189) C_(142,94,190) C_(143,95,191)

#define PL_A \
  P_(96,48,144)  P_(97,49,145)  P_(98,50,146)  P_(99,51,147)  \
  P_(100,52,148) P_(101,53,149) P_(102,54,150) P_(103,55,151) \
  P_(104,56,152) P_(105,57,153) P_(106,58,154) P_(107,59,155) \
  P_(108,60,156) P_(109,61,157) P_(110,62,158) P_(111,63,159)
#define PL_B \
  P_(112,64,160) P_(113,65,161) P_(114,66,162) P_(115,67,163) \
  P_(116,68,164) P_(117,69,165) P_(118,70,166) P_(119,71,167) \
  P_(120,72,168) P_(121,73,169) P_(122,74,170) P_(123,75,171) \
  P_(124,76,172) P_(125,77,173) P_(126,78,174) P_(127,79,175)
#define PL_C \
  P_(128,80,176) P_(129,81,177) P_(130,82,178) P_(131,83,179) \
  P_(132,84,180) P_(133,85,181) P_(134,86,182) P_(135,87,183) \
  P_(136,88,184) P_(137,89,185) P_(138,90,186) P_(139,91,187) \
  P_(140,92,188) P_(141,93,189) P_(142,94,190) P_(143,95,191)

#define EL_A \
  E_(96,48)  E_(97,49)  E_(98,50)  E_(99,51)  E_(100,52) E_(101,53) \
  E_(102,54) E_(103,55) E_(104,56) E_(105,57) E_(106,58) E_(107,59) \
  E_(108,60) E_(109,61) E_(110,62) E_(111,63)
#define EL_B \
  E_(112,64) E_(113,65) E_(114,66) E_(115,67) E_(116,68) E_(117,69) \
  E_(118,70) E_(119,71) E_(120,72) E_(121,73) E_(122,74) E_(123,75) \
  E_(124,76) E_(125,77) E_(126,78) E_(127,79)
#define EL_C \
  E_(128,80) E_(129,81) E_(130,82) E_(131,83) E_(132,84) E_(133,85) \
  E_(134,86) E_(135,87) E_(136,88) E_(137,89) E_(138,90) E_(139,91) \
  E_(140,92) E_(141,93) E_(142,94) E_(143,95)

#define PH_A "s_waitcnt vmcnt(32)\n\t" "s_waitcnt lgkmcnt(0)\n\t" DSR1 CL_A
#define PH_B "s_waitcnt vmcnt(32)\n\t" "s_waitcnt lgkmcnt(0)\n\t" DSR2 CL_B
#define PH_C "s_waitcnt vmcnt(32)\n\t" "s_waitcnt lgkmcnt(0)\n\t" DSR0 CL_C

__global__ __launch_bounds__(64, 1) void scan_lead(
    const int* __restrict__ order, const uint32_t* __restrict__ ov,
    uint32_t* __restrict__ leadws)
{
  __shared__ __align__(16) int sv[ORD_STRIDE];
  const int bc = blockIdx.x;                // b*CLS + c
  const int b  = bc / CLS;
  const int l  = threadIdx.x;
  // stage sorted order into LDS (single wave, coalesced int4)
  {
    const int4* src = (const int4*)(order + (size_t)bc * ORD_STRIDE);
    int4* dst = (int4*)sv;
    for (int i = l; i < ORD_STRIDE / 4; i += 64) dst[i] = src[i];
  }
  const int l4 = l << 2;
  const uint32_t cb = (uint32_t)(uintptr_t)(&sv[0]);   // LDS byte offset
  const uint32_t* rowb = ov + (size_t)b * N_ * NW;
  uint32_t vlead;
  asm volatile(
    "s_waitcnt vmcnt(0) lgkmcnt(0)\n\t"
    "v_mov_b32 v32, %[LN]\n\t"
    "v_mov_b32 v33, %[L4]\n\t"
    "v_mov_b32 v34, 0\n\t"
    "v_mov_b32 v39, %[CB]\n\t"
    "v_mov_b32 v45, 1\n\t"
    DSR0 "s_waitcnt lgkmcnt(0)\n\t" PL_A
    DSR1 "s_waitcnt lgkmcnt(0)\n\t" PL_B
    DSR2 "s_waitcnt lgkmcnt(0)\n\t" PL_C
    DSR0
    "s_mov_b32 s41, 41\n\t"
    "LSCAN%=:\n\t"
    PH_A PH_B PH_C
    "s_sub_u32 s41, s41, 1\n\t"
    "s_cmp_lg_u32 s41, 0\n\t"
    "s_cbranch_scc1 LSCAN%=\n\t"
    PH_A PH_B                               // t = 123, 124 (last issuing phases)
    "s_waitcnt vmcnt(32)\n\t" EL_C          // t = 125
    "s_waitcnt vmcnt(16)\n\t" EL_A          // t = 126
    "s_waitcnt vmcnt(0)\n\t"  EL_B          // t = 127
    "v_mov_b32 %[LD], v34\n\t"
    : [LD] "=v"(vlead)
    : [LN] "v"(l), [L4] "v"(l4), [CB] "v"(cb), [B] "s"(rowb)
    : "memory", "scc", "s40", "s41", "s46", "s47", "s48", "s49",
      "v32","v33","v34","v35","v36","v37","v38","v39","v44","v45",
      "v48","v49","v50","v51","v52","v53","v54","v55",
      "v56","v57","v58","v59","v60","v61","v62","v63","v64","v65","v66","v67",
      "v68","v69","v70","v71","v72","v73","v74","v75","v76","v77","v78","v79",
      "v80","v81","v82","v83","v84","v85","v86","v87","v88","v89","v90","v91",
      "v92","v93","v94","v95","v96","v97","v98","v99","v100","v101","v102","v103",
      "v104","v105","v106","v107","v108","v109","v110","v111","v112","v113","v114","v115",
      "v116","v117","v118","v119","v120","v121","v122","v123","v124","v125","v126","v127",
      "v128","v129","v130","v131","v132","v133","v134","v135","v136","v137","v138","v139",
      "v140","v141","v142","v143","v144","v145","v146","v147","v148","v149","v150","v151",
      "v152","v153","v154","v155","v156","v157","v158","v159","v160","v161","v162","v163",
      "v164","v165","v166","v167","v168","v169","v170","v171","v172","v173","v174","v175",
      "v176","v177","v178","v179","v180","v181","v182","v183","v184","v185","v186","v187",
      "v188","v189","v190","v191");
  leadws[bc * NW + l] = vlead;
}

// ---------------- Kernel D: parallel extraction (wave per box) --------------
// match[n] = original index of the min-rank leader overlapping n (== greedy
// claimant), or -1 if score<=sthr. Coalesced 256B row read per n; per-lane
// bit scan + 6-step shfl_xor min-reduce.
__global__ __launch_bounds__(256) void extract_match(
    const uint32_t* __restrict__ ov, const int* __restrict__ rk,
    const uint32_t* __restrict__ sup0ws, const uint32_t* __restrict__ leadws,
    int* __restrict__ match)
{
  __shared__ __align__(16) int rk_s[N_];
  __shared__ uint32_t lead_s[NW];
  __shared__ uint32_t sup_s[NW];
  const int bc  = blockIdx.x >> 4;          // b*CLS + c
  const int seg = blockIdx.x & 15;          // 128 boxes per block
  const int b   = bc / CLS;
  {
    const int4* src = (const int4*)(rk + (size_t)bc * N_);
    int4* dst = (int4*)rk_s;
    for (int i = threadIdx.x; i < N_ / 4; i += 256) dst[i] = src[i];
    if (threadIdx.x < NW) {
      lead_s[threadIdx.x] = leadws[bc * NW + threadIdx.x];
      sup_s[threadIdx.x]  = sup0ws[bc * NW + threadIdx.x];
    }
  }
  __syncthreads();
  const int wv = threadIdx.x >> 6;
  const int l  = threadIdx.x & 63;
  const uint32_t gl = lead_s[l];
  const uint32_t* Mb = ov + (size_t)b * N_ * NW;
  #pragma unroll 4
  for (int j = 0; j < 32; ++j) {
    const int n = seg * 128 + wv * 32 + j;
    uint32_t bits = Mb[(size_t)n * NW + l] & gl;   // coalesced 256B row
    int minp = 0x7FFFFFFF;
    while (bits) {                          // rare: overlapping leaders
      const int k = __ffs(bits) - 1;
      bits &= bits - 1;
      const int jj = (l << 5) + k;
      const int pk = (rk_s[jj] << 11) | jj;
      minp = (pk < minp) ? pk : minp;
    }
    #pragma unroll
    for (int m = 32; m; m >>= 1) {
      const int o = __shfl_xor(minp, m);
      minp = (o < minp) ? o : minp;
    }
    const bool below = (sup_s[n >> 5] >> (n & 31)) & 1u;
    if (l == 0)
      match[(size_t)bc * N_ + n] =
          (below || minp == 0x7FFFFFFF) ? -1 : (minp & 2047);
  }
}

extern "C" void kernel_launch(void* const* d_in, const int* in_sizes, int n_in,
                              void* d_out, int out_size, void* d_ws, size_t ws_size,
                              hipStream_t stream)
{
  const float4* boxes  = (const float4*)d_in[0];   // [B,N,4] f32
  const float*  scores = (const float*)d_in[1];    // [B,C,N] f32
  const float*  iouthr = (const float*)d_in[2];    // [1]
  const float*  scthr  = (const float*)d_in[3];    // [1]
  int* match = (int*)d_out;                        // [B,C,N] int32

  char* ws = (char*)d_ws;
  uint32_t* ov    = (uint32_t*)ws;                                     // 2 MiB
  int*      order = (int*)(ws + (size_t)B_ * N_ * NW * 4);
  int*      rk    = (int*)((char*)order + (size_t)B_ * CLS * ORD_STRIDE * 4);
  uint32_t* sup0  = (uint32_t*)((char*)rk + (size_t)B_ * CLS * N_ * 4);
  uint32_t* leadw = (uint32_t*)((char*)sup0 + (size_t)B_ * CLS * NW * 4);

  build_mask   <<<dim3(256),      dim3(256), 0, stream>>>(boxes, iouthr, ov);
  sort_init    <<<dim3(B_ * CLS), dim3(256), 0, stream>>>(scores, scthr, order, rk, sup0);
  scan_lead    <<<dim3(B_ * CLS), dim3(64),  0, stream>>>(order, ov, leadw);
  extract_match<<<dim3(256),      dim3(256), 0, stream>>>(ov, rk, sup0, leadw, match);
}